// Round 5
// baseline (61.020 us; speedup 1.0000x reference)
//
#include <hip/hip_runtime.h>

// 3x3 valid cross-correlation + bias, fp32.
// x: 6144x6144, k: 3x3, bias scalar -> out: 6142x6142.
// R4: ROWS 8 -> 16 (rolling 5-row register window keeps VGPR flat at ~32;
// row read amplification 1.25x -> 1.125x). float4+float2 input loads,
// nontemporal float2 output stores (8B-aligned: row stride 6142 and c0
// both even), 32-bit indexing.

#define W_IN  6144
#define H_IN  6144
#define OW    6142
#define OH    6142
#define ROWS  16
#define NCOLT 1536   // 6142/4 column-group threads (last thread covers cols 6140-6141)

typedef float f32x2 __attribute__((ext_vector_type(2)));
typedef float f32x4 __attribute__((ext_vector_type(4)));

template <bool INTERIOR>
__device__ __forceinline__ void body_main(const float* __restrict__ x,
                                          float* __restrict__ out,
                                          int c0, int r0,
                                          float k00, float k01, float k02,
                                          float k10, float k11, float k12,
                                          float k20, float k21, float k22,
                                          float bv)
{
    // Rolling 5-row window; all indices constant after full unroll.
    float v[5][6];

#pragma unroll
    for (int r = 0; r < 4; ++r) {
        const int rr = r0 + r;
        if (INTERIOR || rr < H_IN) {
            const float* p = x + rr * W_IN + c0;
            const f32x4 a = *reinterpret_cast<const f32x4*>(p);
            const f32x2 c = *reinterpret_cast<const f32x2*>(p + 4);
            v[r][0] = a.x; v[r][1] = a.y; v[r][2] = a.z; v[r][3] = a.w;
            v[r][4] = c.x; v[r][5] = c.y;
        } else {
#pragma unroll
            for (int j = 0; j < 6; ++j) v[r][j] = 0.f;
        }
    }

#pragma unroll
    for (int m = 0; m < ROWS; ++m) {
        // Load row r0+m+4 (2 rows ahead of the row consumed last by output m).
        if (m + 4 <= ROWS + 1) {
            const int slot = (m + 4) % 5;
            const int rr = r0 + m + 4;
            if (INTERIOR || rr < H_IN) {
                const float* p = x + rr * W_IN + c0;
                const f32x4 a = *reinterpret_cast<const f32x4*>(p);
                const f32x2 c = *reinterpret_cast<const f32x2*>(p + 4);
                v[slot][0] = a.x; v[slot][1] = a.y; v[slot][2] = a.z; v[slot][3] = a.w;
                v[slot][4] = c.x; v[slot][5] = c.y;
            } else {
#pragma unroll
                for (int j = 0; j < 6; ++j) v[slot][j] = 0.f;
            }
        }

        const int rr = r0 + m;
        if (INTERIOR || rr < OH) {
            const int w0 = m % 5, w1 = (m + 1) % 5, w2 = (m + 2) % 5;
            float acc[4];
#pragma unroll
            for (int j = 0; j < 4; ++j) {
                acc[j] = bv
                    + v[w0][j] * k00 + v[w0][j + 1] * k01 + v[w0][j + 2] * k02
                    + v[w1][j] * k10 + v[w1][j + 1] * k11 + v[w1][j + 2] * k12
                    + v[w2][j] * k20 + v[w2][j + 1] * k21 + v[w2][j + 2] * k22;
            }
            float* po = out + rr * OW + c0;
            f32x2 s0; s0.x = acc[0]; s0.y = acc[1];
            f32x2 s1; s1.x = acc[2]; s1.y = acc[3];
            __builtin_nontemporal_store(s0, reinterpret_cast<f32x2*>(po));
            __builtin_nontemporal_store(s1, reinterpret_cast<f32x2*>(po + 2));
        }
    }
}

template <bool INTERIOR>
__device__ __forceinline__ void body_tail(const float* __restrict__ x,
                                          float* __restrict__ out,
                                          int c0, int r0,
                                          float k00, float k01, float k02,
                                          float k10, float k11, float k12,
                                          float k20, float k21, float k22,
                                          float bv)
{
    // c0 == 6140: output cols 6140..6141, input cols 6140..6143 (one float4).
    float v[5][4];

#pragma unroll
    for (int r = 0; r < 4; ++r) {
        const int rr = r0 + r;
        if (INTERIOR || rr < H_IN) {
            const f32x4 a = *reinterpret_cast<const f32x4*>(x + rr * W_IN + c0);
            v[r][0] = a.x; v[r][1] = a.y; v[r][2] = a.z; v[r][3] = a.w;
        } else {
#pragma unroll
            for (int j = 0; j < 4; ++j) v[r][j] = 0.f;
        }
    }

#pragma unroll
    for (int m = 0; m < ROWS; ++m) {
        if (m + 4 <= ROWS + 1) {
            const int slot = (m + 4) % 5;
            const int rr = r0 + m + 4;
            if (INTERIOR || rr < H_IN) {
                const f32x4 a = *reinterpret_cast<const f32x4*>(x + rr * W_IN + c0);
                v[slot][0] = a.x; v[slot][1] = a.y; v[slot][2] = a.z; v[slot][3] = a.w;
            } else {
#pragma unroll
                for (int j = 0; j < 4; ++j) v[slot][j] = 0.f;
            }
        }

        const int rr = r0 + m;
        if (INTERIOR || rr < OH) {
            const int w0 = m % 5, w1 = (m + 1) % 5, w2 = (m + 2) % 5;
            float a0 = bv
                + v[w0][0] * k00 + v[w0][1] * k01 + v[w0][2] * k02
                + v[w1][0] * k10 + v[w1][1] * k11 + v[w1][2] * k12
                + v[w2][0] * k20 + v[w2][1] * k21 + v[w2][2] * k22;
            float a1 = bv
                + v[w0][1] * k00 + v[w0][2] * k01 + v[w0][3] * k02
                + v[w1][1] * k10 + v[w1][2] * k11 + v[w1][3] * k12
                + v[w2][1] * k20 + v[w2][2] * k21 + v[w2][3] * k22;
            f32x2 s0; s0.x = a0; s0.y = a1;
            __builtin_nontemporal_store(s0, reinterpret_cast<f32x2*>(out + rr * OW + c0));
        }
    }
}

__global__ __launch_bounds__(256, 4)
void corr2d_kernel(const float* __restrict__ x,
                   const float* __restrict__ kk,
                   const float* __restrict__ bias,
                   float* __restrict__ out) {
    const int t  = blockIdx.x * 256 + threadIdx.x;   // 0..1535
    const int c0 = t << 2;                           // 0,4,...,6140
    const int r0 = blockIdx.y * ROWS;

    const float k00 = kk[0], k01 = kk[1], k02 = kk[2];
    const float k10 = kk[3], k11 = kk[4], k12 = kk[5];
    const float k20 = kk[6], k21 = kk[7], k22 = kk[8];
    const float bv = bias[0];

    const bool interior = (r0 + ROWS + 1) < H_IN;    // input rows r0..r0+ROWS+1 all valid

    if (c0 + 4 <= OW) {
        if (interior) body_main<true >(x, out, c0, r0, k00, k01, k02, k10, k11, k12, k20, k21, k22, bv);
        else          body_main<false>(x, out, c0, r0, k00, k01, k02, k10, k11, k12, k20, k21, k22, bv);
    } else {
        if (interior) body_tail<true >(x, out, c0, r0, k00, k01, k02, k10, k11, k12, k20, k21, k22, bv);
        else          body_tail<false>(x, out, c0, r0, k00, k01, k02, k10, k11, k12, k20, k21, k22, bv);
    }
}

extern "C" void kernel_launch(void* const* d_in, const int* in_sizes, int n_in,
                              void* d_out, int out_size, void* d_ws, size_t ws_size,
                              hipStream_t stream) {
    const float* x    = (const float*)d_in[0];
    const float* k    = (const float*)d_in[1];
    const float* bias = (const float*)d_in[2];
    float* out        = (float*)d_out;

    dim3 block(256, 1, 1);
    dim3 grid(NCOLT / 256, (OH + ROWS - 1) / ROWS, 1);   // 6 x 384
    corr2d_kernel<<<grid, block, 0, stream>>>(x, k, bias, out);
}

// Round 6
// 51.068 us; speedup vs baseline: 1.1949x; 1.1949x over previous
//
#include <hip/hip_runtime.h>

// 3x3 valid cross-correlation + bias, fp32.
// x: 6144x6144, k: 3x3, bias scalar -> out: 6142x6142.
// R5: ROWS=8 with ALL 10 row-loads issued upfront (deep MLP: ~20
// outstanding loads/wave vs ~2 for the rolling window) + chunked
// bijective XCD swizzle (y-adjacent bands share halo rows -> same-XCD L2).
// float4+float2 input loads, nontemporal float2 output stores
// (8B-aligned: row stride 6142 and c0 both even), 32-bit indexing.

#define W_IN  6144
#define H_IN  6144
#define OW    6142
#define OH    6142
#define ROWS  8
#define GRID_X 6      // column-strip blocks (6*256 threads * 4 cols = 6144 >= 6142)
#define GRID_Y 768    // row bands of 8
#define NWG   (GRID_X * GRID_Y)   // 4608 = 8 XCDs * 576
#define WG_PER_XCD (NWG / 8)      // 576

typedef float f32x2 __attribute__((ext_vector_type(2)));
typedef float f32x4 __attribute__((ext_vector_type(4)));

template <bool INTERIOR>
__device__ __forceinline__ void body_main(const float* __restrict__ x,
                                          float* __restrict__ out,
                                          int c0, int r0,
                                          float k00, float k01, float k02,
                                          float k10, float k11, float k12,
                                          float k20, float k21, float k22,
                                          float bv)
{
    // All 10 rows loaded upfront: 30 VMEM loads in flight before first use.
    float v[ROWS + 2][6];
#pragma unroll
    for (int r = 0; r < ROWS + 2; ++r) {
        const int rr = r0 + r;
        if (INTERIOR || rr < H_IN) {
            const float* p = x + rr * W_IN + c0;
            const f32x4 a = *reinterpret_cast<const f32x4*>(p);
            const f32x2 c = *reinterpret_cast<const f32x2*>(p + 4);
            v[r][0] = a.x; v[r][1] = a.y; v[r][2] = a.z; v[r][3] = a.w;
            v[r][4] = c.x; v[r][5] = c.y;
        } else {
#pragma unroll
            for (int j = 0; j < 6; ++j) v[r][j] = 0.f;
        }
    }

#pragma unroll
    for (int m = 0; m < ROWS; ++m) {
        const int rr = r0 + m;
        if (INTERIOR || rr < OH) {
            float acc[4];
#pragma unroll
            for (int j = 0; j < 4; ++j) {
                acc[j] = bv
                    + v[m + 0][j] * k00 + v[m + 0][j + 1] * k01 + v[m + 0][j + 2] * k02
                    + v[m + 1][j] * k10 + v[m + 1][j + 1] * k11 + v[m + 1][j + 2] * k12
                    + v[m + 2][j] * k20 + v[m + 2][j + 1] * k21 + v[m + 2][j + 2] * k22;
            }
            float* po = out + rr * OW + c0;
            f32x2 s0; s0.x = acc[0]; s0.y = acc[1];
            f32x2 s1; s1.x = acc[2]; s1.y = acc[3];
            __builtin_nontemporal_store(s0, reinterpret_cast<f32x2*>(po));
            __builtin_nontemporal_store(s1, reinterpret_cast<f32x2*>(po + 2));
        }
    }
}

template <bool INTERIOR>
__device__ __forceinline__ void body_tail(const float* __restrict__ x,
                                          float* __restrict__ out,
                                          int c0, int r0,
                                          float k00, float k01, float k02,
                                          float k10, float k11, float k12,
                                          float k20, float k21, float k22,
                                          float bv)
{
    // c0 == 6140: output cols 6140..6141, input cols 6140..6143 (one float4).
    float v[ROWS + 2][4];
#pragma unroll
    for (int r = 0; r < ROWS + 2; ++r) {
        const int rr = r0 + r;
        if (INTERIOR || rr < H_IN) {
            const f32x4 a = *reinterpret_cast<const f32x4*>(x + rr * W_IN + c0);
            v[r][0] = a.x; v[r][1] = a.y; v[r][2] = a.z; v[r][3] = a.w;
        } else {
#pragma unroll
            for (int j = 0; j < 4; ++j) v[r][j] = 0.f;
        }
    }

#pragma unroll
    for (int m = 0; m < ROWS; ++m) {
        const int rr = r0 + m;
        if (INTERIOR || rr < OH) {
            float a0 = bv
                + v[m + 0][0] * k00 + v[m + 0][1] * k01 + v[m + 0][2] * k02
                + v[m + 1][0] * k10 + v[m + 1][1] * k11 + v[m + 1][2] * k12
                + v[m + 2][0] * k20 + v[m + 2][1] * k21 + v[m + 2][2] * k22;
            float a1 = bv
                + v[m + 0][1] * k00 + v[m + 0][2] * k01 + v[m + 0][3] * k02
                + v[m + 1][1] * k10 + v[m + 1][2] * k11 + v[m + 1][3] * k12
                + v[m + 2][1] * k20 + v[m + 2][2] * k21 + v[m + 2][3] * k22;
            f32x2 s0; s0.x = a0; s0.y = a1;
            __builtin_nontemporal_store(s0, reinterpret_cast<f32x2*>(out + rr * OW + c0));
        }
    }
}

__global__ __launch_bounds__(256)
void corr2d_kernel(const float* __restrict__ x,
                   const float* __restrict__ kk,
                   const float* __restrict__ bias,
                   float* __restrict__ out) {
    // Chunked bijective XCD swizzle: consecutive wg on one XCD are
    // y-adjacent bands of the same column strip -> halo rows L2-hit.
    const int id = blockIdx.x;                        // 0..4607
    const int wg = (id & 7) * WG_PER_XCD + (id >> 3); // bijection (4608 % 8 == 0)
    const int bx = wg / GRID_Y;                       // 0..5   column strip
    const int by = wg - bx * GRID_Y;                  // 0..767 row band

    const int t  = bx * 256 + (int)threadIdx.x;       // 0..1535
    const int c0 = t << 2;                            // 0,4,...,6140
    const int r0 = by * ROWS;

    const float k00 = kk[0], k01 = kk[1], k02 = kk[2];
    const float k10 = kk[3], k11 = kk[4], k12 = kk[5];
    const float k20 = kk[6], k21 = kk[7], k22 = kk[8];
    const float bv = bias[0];

    const bool interior = (r0 + ROWS + 1) < H_IN;     // input rows r0..r0+ROWS+1 all valid

    if (c0 + 4 <= OW) {
        if (interior) body_main<true >(x, out, c0, r0, k00, k01, k02, k10, k11, k12, k20, k21, k22, bv);
        else          body_main<false>(x, out, c0, r0, k00, k01, k02, k10, k11, k12, k20, k21, k22, bv);
    } else {
        if (interior) body_tail<true >(x, out, c0, r0, k00, k01, k02, k10, k11, k12, k20, k21, k22, bv);
        else          body_tail<false>(x, out, c0, r0, k00, k01, k02, k10, k11, k12, k20, k21, k22, bv);
    }
}

extern "C" void kernel_launch(void* const* d_in, const int* in_sizes, int n_in,
                              void* d_out, int out_size, void* d_ws, size_t ws_size,
                              hipStream_t stream) {
    const float* x    = (const float*)d_in[0];
    const float* k    = (const float*)d_in[1];
    const float* bias = (const float*)d_in[2];
    float* out        = (float*)d_out;

    dim3 block(256, 1, 1);
    dim3 grid(NWG, 1, 1);   // 4608 blocks, 1D, swizzled in-kernel
    corr2d_kernel<<<grid, block, 0, stream>>>(x, k, bias, out);
}